// Round 7
// baseline (7602.259 us; speedup 1.0000x reference)
//
#include <hip/hip_runtime.h>
#include <hip/hip_bf16.h>

typedef _Float16 f16;
typedef _Float16 f16x8 __attribute__((ext_vector_type(8)));
typedef float f32x4 __attribute__((ext_vector_type(4)));

#define B_ 128
#define T_ 256
#define D_ 1280
#define G3_ 3840
#define C_ 100
#define TB_ 32768  /* T_*B_ */
#define NBUF 16    /* rotating h buffers */

// ---- workspace layout (bytes) ----
#define O_H16  0ull                 // f16 [NBUF][B_][D_]  (5.25 MB, inside seqb region) - V0
#define O_SEQB 0ull                 // f16 [TB_][D_]   (row = t*128+b)
#define O_HV1  8388608ull           // V1/V3 h scratch (5.25 MB)
#define O_PRIVA 16777216ull         // V3 private A: 160 blocks x 160 KB = 25.6 MB
#define O_HV2  50331648ull          // V2 h scratch (reads only; seqb leftovers)
#define O_H32S 79691776ull          // scratch h32 for diagnostic variants
#define O_WIH  83886080ull          // f16 [G3_][D_]
#define O_WHH  93716480ull          // f16 [G3_][D_]
#define O_XP   103546880ull         // f16 [T_][80][3][128][16] compact slabs
#define O_H32  355860480ull         // f32 [B_][D_]
#define O_BAR  356515840ull         // u32 counters: 4 variants x 1024 u32

// ---------------- conversion / init ----------------
__global__ void k_convert(const float* __restrict__ seq, const float* __restrict__ wih,
                          const float* __restrict__ whh, f16* __restrict__ seqb,
                          f16* __restrict__ wih16, f16* __restrict__ whh16,
                          unsigned* __restrict__ bar) {
  if (blockIdx.x == 0) {
    for (int j = threadIdx.x; j < 4096; j += 256)
      __hip_atomic_store(bar + j, 0u, __ATOMIC_RELAXED, __HIP_MEMORY_SCOPE_AGENT);
  }
  const long NSEQ = (long)TB_ * (D_ / 8);
  const long NW = (long)G3_ * (D_ / 8);
  const long total = NSEQ + 2 * NW;
  for (long i = (long)blockIdx.x * blockDim.x + threadIdx.x; i < total;
       i += (long)gridDim.x * blockDim.x) {
    const float* src;
    f16* dst;
    if (i < NSEQ) {
      long row = i / (D_ / 8), c = i % (D_ / 8);
      long t = row >> 7, b = row & 127;
      src = seq + ((b * T_ + t) * (long)D_ + c * 8);
      dst = seqb + (row * (long)D_ + c * 8);
    } else if (i < NSEQ + NW) {
      long j = i - NSEQ;
      src = wih + j * 8;
      dst = wih16 + j * 8;
    } else {
      long j = i - NSEQ - NW;
      src = whh + j * 8;
      dst = whh16 + j * 8;
    }
    float4 a = *(const float4*)src, b4 = *(const float4*)(src + 4);
    f16x8 o;
    o[0] = (f16)a.x; o[1] = (f16)a.y; o[2] = (f16)a.z; o[3] = (f16)a.w;
    o[4] = (f16)b4.x; o[5] = (f16)b4.y; o[6] = (f16)b4.z; o[7] = (f16)b4.w;
    *(f16x8*)dst = o;
  }
}

// ---------------- x_proj GEMM -> compact slab layout [t][cg][g][b][c16] ----------------
__device__ __forceinline__ void gl_lds16(const f16* g, f16* lds) {
  __builtin_amdgcn_global_load_lds((const __attribute__((address_space(1))) void*)g,
                                   (__attribute__((address_space(3))) void*)lds, 16, 0, 0);
}

__global__ __launch_bounds__(256) void k_xproj(const f16* __restrict__ A, const f16* __restrict__ Bw,
                                               const float* __restrict__ bih, f16* __restrict__ Cout) {
  __shared__ f16 Alds[128 * 32];
  __shared__ f16 Blds[128 * 32];
  int bid = blockIdx.x;
  int sb = bid / 240;
  int wi = bid % 240;
  int bm = sb * 8 + (wi & 7);
  int bn = wi >> 3;
  long brow = (long)bm * 128;
  int bcol = bn * 128;
  int tid = threadIdx.x, w = tid >> 6, l = tid & 63;
  int wm = w & 1, wn = w >> 1;

  f32x4 acc[4][4] = {};

  int sr = w * 32 + (l >> 2);
  int sc = (l & 3) * 8;
  const f16* gA = A + (brow + sr) * (long)D_ + sc;
  const f16* gB = Bw + (long)(bcol + sr) * D_ + sc;
  f16* lAw = Alds + (w * 32) * 32;
  f16* lBw = Blds + (w * 32) * 32;

  int fr = l & 15, fc = (l >> 4) * 8;

  for (int kb = 0; kb < 40; ++kb) {
    const f16* a0 = gA + kb * 32;
    const f16* b0 = gB + kb * 32;
    gl_lds16(a0, lAw);
    gl_lds16(a0 + 16 * D_, lAw + 16 * 32);
    gl_lds16(b0, lBw);
    gl_lds16(b0 + 16 * D_, lBw + 16 * 32);
    __syncthreads();
    f16x8 af[4], bf[4];
#pragma unroll
    for (int mt = 0; mt < 4; ++mt) af[mt] = *(const f16x8*)(Alds + (wm * 64 + mt * 16 + fr) * 32 + fc);
#pragma unroll
    for (int nt = 0; nt < 4; ++nt) bf[nt] = *(const f16x8*)(Blds + (wn * 64 + nt * 16 + fr) * 32 + fc);
#pragma unroll
    for (int mt = 0; mt < 4; ++mt)
#pragma unroll
      for (int nt = 0; nt < 4; ++nt)
        acc[mt][nt] = __builtin_amdgcn_mfma_f32_16x16x32_f16(af[mt], bf[nt], acc[mt][nt], 0, 0, 0);
    __syncthreads();
  }
#pragma unroll
  for (int nt = 0; nt < 4; ++nt) {
    int col = bcol + wn * 64 + nt * 16 + fr;
    int g = col / D_;
    int dcol = col - g * D_;
    int cg = dcol >> 4, c16 = dcol & 15;
    float bv = bih[col];
    f16* base = Cout + (((long)bm * 80 + cg) * 3 + g) * 2048 + c16;
#pragma unroll
    for (int mt = 0; mt < 4; ++mt) {
#pragma unroll
      for (int i = 0; i < 4; ++i) {
        int b = wm * 64 + mt * 16 + (l >> 4) * 4 + i;
        base[b * 16] = (f16)(acc[mt][nt][i] + bv);
      }
    }
  }
}

// ---------------- GRU scan (ABLATION TEMPLATE) ----------------
// MODE 0 = real; 1 = NOBAR (no signal/poll); 2 = NOSTORE (no h writes);
// MODE 3 = PRIVA (A-operand from private always-hot region).
template <int MODE>
__global__ __launch_bounds__(256, 1) void k_scan_t(const f16* __restrict__ whh16,
                                                   const f16* __restrict__ xproj,
                                                   const float* __restrict__ bhh,
                                                   f16* __restrict__ h16, float* __restrict__ h32,
                                                   unsigned* __restrict__ bar,
                                                   const f16* __restrict__ privA) {
  __shared__ f16 wlds[3 * 16 * D_];  // 120 KB, wave-linear chunk layout
  int wg = blockIdx.x;
  int rg = (wg & 7) >> 2;                    // XCD-pure rowgroup
  int q = wg >> 3;                           // 0..19
  int cg = q * 4 + (wg & 3);                 // 0..79
  int r0 = rg * 64, d0 = cg * 16;
  int tid = threadIdx.x, w = tid >> 6, l = tid & 63;
  int wr0 = r0 + w * 16;
  int fr = l & 15, fq = l >> 4;
  int mycol = d0 + fr;
  int shard = ((q & 3) << 2) | (wg & 3);     // 16 shards/rowgroup, 5 blocks each
  unsigned* mycnt = bar + (rg * 16 + shard) * 32;
  int koff = (q & 3) * 10;

  for (int qq = tid; qq < 3 * 16 * 160; qq += 256) {
    int rowg = qq / 160, c8 = qq % 160;
    int g = rowg >> 4, j = rowg & 15;
    int kb = c8 >> 2, kq = c8 & 3;
    uint4 v = *(const uint4*)(whh16 + ((long)(g * D_ + d0 + j)) * D_ + c8 * 8);
    *(uint4*)(wlds + (((kb * 3 + g) * 4 + kq) * 16 + j) * 8) = v;
  }
#pragma unroll
  for (int i = 0; i < 4; ++i) {
    if ((fr & 1) == 0) {
      unsigned* p = (unsigned*)(h16 + (wr0 + fq * 4 + i) * D_ + mycol);
      __hip_atomic_store(p, 0u, __ATOMIC_RELAXED, __HIP_MEMORY_SCOPE_AGENT);
    }
  }

  float bh0 = bhh[0 * D_ + mycol];
  float bh1 = bhh[1 * D_ + mycol];
  float bh2 = bhh[2 * D_ + mycol];
  float hreg[4] = {0.f, 0.f, 0.f, 0.f};
  f16 xg0[4], xg1[4], xg2[4];

  auto prefetch_x = [&](int tt) {
    const f16* xs = xproj + (((long)tt * 80 + cg) * 3) * 2048 + fr;
#pragma unroll
    for (int i = 0; i < 4; ++i) {
      int b = wr0 + fq * 4 + i;
      xg0[i] = xs[0 * 2048 + b * 16];
      xg1[i] = xs[1 * 2048 + b * 16];
      xg2[i] = xs[2 * 2048 + b * 16];
    }
  };
  auto poll16 = [&](unsigned target) {
    unsigned it = 0;
    for (;;) {
      unsigned v = target;
      if (l < 16)
        v = __hip_atomic_load(bar + (rg * 16 + l) * 32, __ATOMIC_RELAXED, __HIP_MEMORY_SCOPE_AGENT);
      if (__all(v >= target)) break;
      __builtin_amdgcn_s_sleep(1);
      if (++it > 500000u) {
        if (l < 16)
          v = __hip_atomic_fetch_add(bar + (rg * 16 + l) * 32, 0u, __ATOMIC_RELAXED,
                                     __HIP_MEMORY_SCOPE_AGENT);
        if (__all(v >= target)) break;
        it = 0;
      }
    }
  };

  prefetch_x(0);

  __syncthreads();
  if constexpr (MODE != 1) {
    if (tid == 0)
      __hip_atomic_fetch_add(mycnt, 1u, __ATOMIC_RELAXED, __HIP_MEMORY_SCOPE_AGENT);
    if (tid < 64) {
      poll16(5u);
      if (tid == 0) __builtin_amdgcn_fence(__ATOMIC_ACQUIRE, "agent");
    }
  }
  __syncthreads();

  unsigned tgt = 10u;
  for (int t = 0; t < T_; ++t) {
    const f16* arow;
    if constexpr (MODE == 3) {
      arow = privA + (long)wg * 81920 + (w * 16 + fr) * (long)D_ + fq * 8;
    } else {
      const f16* hc = h16 + (t & (NBUF - 1)) * (B_ * D_);
      arow = hc + (wr0 + fr) * (long)D_ + fq * 8;
    }
    f32x4 acc0 = {}, acc1 = {}, acc2 = {};
#pragma unroll 10
    for (int ii = 0; ii < 40; ++ii) {
      int kb = ii + koff;
      kb = (kb >= 40) ? kb - 40 : kb;
      f16x8 a = *(const f16x8*)(arow + kb * 32);
      const f16* wb = wlds + kb * 1536 + (fq * 16 + fr) * 8;
      f16x8 b0 = *(const f16x8*)(wb);
      f16x8 b1 = *(const f16x8*)(wb + 512);
      f16x8 b2 = *(const f16x8*)(wb + 1024);
      acc0 = __builtin_amdgcn_mfma_f32_16x16x32_f16(a, b0, acc0, 0, 0, 0);
      acc1 = __builtin_amdgcn_mfma_f32_16x16x32_f16(a, b1, acc1, 0, 0, 0);
      acc2 = __builtin_amdgcn_mfma_f32_16x16x32_f16(a, b2, acc2, 0, 0, 0);
    }
    float hnew[4];
#pragma unroll
    for (int i = 0; i < 4; ++i) {
      float gr = (float)xg0[i], gz = (float)xg1[i], gn = (float)xg2[i];
      float r = 1.f / (1.f + __expf(-(gr + acc0[i] + bh0)));
      float z = 1.f / (1.f + __expf(-(gz + acc1[i] + bh1)));
      float pn = gn + r * (acc2[i] + bh2);
      pn = fminf(fmaxf(pn, -30.f), 30.f);
      float e = __expf(-2.f * pn);
      float n = (1.f - e) / (1.f + e);
      hnew[i] = (1.f - z) * n + z * hreg[i];
      hreg[i] = hnew[i];
    }
    if (t == T_ - 1) break;
    if constexpr (MODE != 2) {
      f16* hn = h16 + ((t + 1) & (NBUF - 1)) * (B_ * D_);
#pragma unroll
      for (int i = 0; i < 4; ++i) {
        int row = wr0 + fq * 4 + i;
        unsigned short bits = __builtin_bit_cast(unsigned short, (f16)hnew[i]);
        unsigned other = (unsigned)__shfl_xor((int)bits, 1);
        if ((fr & 1) == 0) {
          unsigned val = (unsigned)bits | (other << 16);
          unsigned* p = (unsigned*)(hn + row * D_ + mycol);
          __hip_atomic_store(p, val, __ATOMIC_RELAXED, __HIP_MEMORY_SCOPE_AGENT);
        }
      }
    }
    __syncthreads();
    if constexpr (MODE != 1) {
      if (tid == 0)
        __hip_atomic_fetch_add(mycnt, 1u, __ATOMIC_RELAXED, __HIP_MEMORY_SCOPE_AGENT);
    }
    prefetch_x(t + 1);
    if constexpr (MODE != 1) {
      if (tid < 64) {
        poll16(tgt);
        if (tid == 0 && (((t + 1) & (NBUF - 1)) == 0))
          __builtin_amdgcn_fence(__ATOMIC_ACQUIRE, "agent");
      }
    }
    __syncthreads();
    tgt += 5u;
  }
#pragma unroll
  for (int i = 0; i < 4; ++i) h32[(wr0 + fq * 4 + i) * D_ + mycol] = hreg[i];
}

// ---------------- scores ----------------
__global__ __launch_bounds__(256) void k_scores(const float* __restrict__ h32,
                                                const float* __restrict__ cand,
                                                float* __restrict__ out) {
  int gw = blockIdx.x * 4 + (threadIdx.x >> 6);
  int l = threadIdx.x & 63;
  int b = gw / C_, c = gw % C_;
  const float* hp = h32 + (long)b * D_;
  const float* cp = cand + ((long)b * C_ + c) * D_;
  float s = 0.f;
#pragma unroll
  for (int q = 0; q < 5; ++q) {
    int d = q * 256 + l * 4;
    float4 hv = *(const float4*)(hp + d);
    float4 cv = *(const float4*)(cp + d);
    s += hv.x * cv.x + hv.y * cv.y + hv.z * cv.z + hv.w * cv.w;
  }
#pragma unroll
  for (int off = 32; off > 0; off >>= 1) s += __shfl_down(s, off);
  if (l == 0) out[(long)b * C_ + c] = s;
}

extern "C" void kernel_launch(void* const* d_in, const int* in_sizes, int n_in, void* d_out,
                              int out_size, void* d_ws, size_t ws_size, hipStream_t stream) {
  const float* seq = (const float*)d_in[0];
  const float* cand = (const float*)d_in[1];
  const float* wih = (const float*)d_in[2];
  const float* whh = (const float*)d_in[3];
  const float* bih = (const float*)d_in[4];
  const float* bhh = (const float*)d_in[5];
  char* ws = (char*)d_ws;
  f16* seqb = (f16*)(ws + O_SEQB);
  f16* wih16 = (f16*)(ws + O_WIH);
  f16* whh16 = (f16*)(ws + O_WHH);
  f16* xp = (f16*)(ws + O_XP);
  f16* h16 = (f16*)(ws + O_H16);
  f16* h16v1 = (f16*)(ws + O_HV1);
  f16* h16v2 = (f16*)(ws + O_HV2);
  const f16* privA = (const f16*)(ws + O_PRIVA);
  float* h32 = (float*)(ws + O_H32);
  float* h32s = (float*)(ws + O_H32S);
  unsigned* bar = (unsigned*)(ws + O_BAR);

  k_convert<<<2048, 256, 0, stream>>>(seq, wih, whh, seqb, wih16, whh16, bar);
  k_xproj<<<7680, 256, 0, stream>>>(seqb, wih16, bih, xp);
  // ---- diagnostics (outputs unused; disjoint state) ----
  k_scan_t<1><<<160, 256, 0, stream>>>(whh16, xp, bhh, h16v1, h32s, bar + 1024, privA);
  k_scan_t<2><<<160, 256, 0, stream>>>(whh16, xp, bhh, h16v2, h32s, bar + 2048, privA);
  k_scan_t<3><<<160, 256, 0, stream>>>(whh16, xp, bhh, h16v1, h32s, bar + 3072, privA);
  // ---- real ----
  k_scan_t<0><<<160, 256, 0, stream>>>(whh16, xp, bhh, h16, h32, bar, privA);
  k_scores<<<3200, 256, 0, stream>>>(h32, cand, (float*)d_out);
}

// Round 8
// 2395.778 us; speedup vs baseline: 3.1732x; 3.1732x over previous
//
#include <hip/hip_runtime.h>
#include <hip/hip_bf16.h>

typedef _Float16 f16;
typedef _Float16 f16x8 __attribute__((ext_vector_type(8)));
typedef float f32x4 __attribute__((ext_vector_type(4)));

#define B_ 128
#define T_ 256
#define D_ 1280
#define G3_ 3840
#define C_ 100
#define TB_ 32768  /* T_*B_ */
#define NBUF 16    /* rotating h buffers */

// ---- workspace layout (bytes) ----
// h buffers overlap the seqb region (seqb dead after k_xproj; rewritten each replay).
#define O_H16  0ull                 // f16 [NBUF][B_][D_]  (5.25 MB)
#define O_SEQB 0ull                 // f16 [TB_][D_]
#define O_WIH  83886080ull          // f16 [G3_][D_]
#define O_WHH  93716480ull          // f16 [G3_][D_]
#define O_XP   103546880ull         // f16 [T_][80][3][128][16] compact slabs
#define O_H32  355860480ull         // f32 [B_][D_]
#define O_BAR  356515840ull         // u32 counters: (rg*40+shard)*32 stride (128B), 320 shards

// ---------------- conversion / init ----------------
__global__ void k_convert(const float* __restrict__ seq, const float* __restrict__ wih,
                          const float* __restrict__ whh, f16* __restrict__ seqb,
                          f16* __restrict__ wih16, f16* __restrict__ whh16,
                          unsigned* __restrict__ bar) {
  if (blockIdx.x == 0) {
    for (int j = threadIdx.x; j < 10240; j += 256)
      __hip_atomic_store(bar + j, 0u, __ATOMIC_RELAXED, __HIP_MEMORY_SCOPE_AGENT);
  }
  const long NSEQ = (long)TB_ * (D_ / 8);
  const long NW = (long)G3_ * (D_ / 8);
  const long total = NSEQ + 2 * NW;
  for (long i = (long)blockIdx.x * blockDim.x + threadIdx.x; i < total;
       i += (long)gridDim.x * blockDim.x) {
    const float* src;
    f16* dst;
    if (i < NSEQ) {
      long row = i / (D_ / 8), c = i % (D_ / 8);
      long t = row >> 7, b = row & 127;
      src = seq + ((b * T_ + t) * (long)D_ + c * 8);
      dst = seqb + (row * (long)D_ + c * 8);
    } else if (i < NSEQ + NW) {
      long j = i - NSEQ;
      src = wih + j * 8;
      dst = wih16 + j * 8;
    } else {
      long j = i - NSEQ - NW;
      src = whh + j * 8;
      dst = whh16 + j * 8;
    }
    float4 a = *(const float4*)src, b4 = *(const float4*)(src + 4);
    f16x8 o;
    o[0] = (f16)a.x; o[1] = (f16)a.y; o[2] = (f16)a.z; o[3] = (f16)a.w;
    o[4] = (f16)b4.x; o[5] = (f16)b4.y; o[6] = (f16)b4.z; o[7] = (f16)b4.w;
    *(f16x8*)dst = o;
  }
}

// ---------------- x_proj GEMM -> compact slab layout [t][cg][g][b][c16] ----------------
__device__ __forceinline__ void gl_lds16(const f16* g, f16* lds) {
  __builtin_amdgcn_global_load_lds((const __attribute__((address_space(1))) void*)g,
                                   (__attribute__((address_space(3))) void*)lds, 16, 0, 0);
}

__global__ __launch_bounds__(256) void k_xproj(const f16* __restrict__ A, const f16* __restrict__ Bw,
                                               const float* __restrict__ bih, f16* __restrict__ Cout) {
  __shared__ f16 Alds[128 * 32];
  __shared__ f16 Blds[128 * 32];
  int bid = blockIdx.x;
  int sb = bid / 240;
  int wi = bid % 240;
  int bm = sb * 8 + (wi & 7);
  int bn = wi >> 3;
  long brow = (long)bm * 128;
  int bcol = bn * 128;
  int tid = threadIdx.x, w = tid >> 6, l = tid & 63;
  int wm = w & 1, wn = w >> 1;

  f32x4 acc[4][4] = {};

  int sr = w * 32 + (l >> 2);
  int sc = (l & 3) * 8;
  const f16* gA = A + (brow + sr) * (long)D_ + sc;
  const f16* gB = Bw + (long)(bcol + sr) * D_ + sc;
  f16* lAw = Alds + (w * 32) * 32;
  f16* lBw = Blds + (w * 32) * 32;

  int fr = l & 15, fc = (l >> 4) * 8;

  for (int kb = 0; kb < 40; ++kb) {
    const f16* a0 = gA + kb * 32;
    const f16* b0 = gB + kb * 32;
    gl_lds16(a0, lAw);
    gl_lds16(a0 + 16 * D_, lAw + 16 * 32);
    gl_lds16(b0, lBw);
    gl_lds16(b0 + 16 * D_, lBw + 16 * 32);
    __syncthreads();
    f16x8 af[4], bf[4];
#pragma unroll
    for (int mt = 0; mt < 4; ++mt) af[mt] = *(const f16x8*)(Alds + (wm * 64 + mt * 16 + fr) * 32 + fc);
#pragma unroll
    for (int nt = 0; nt < 4; ++nt) bf[nt] = *(const f16x8*)(Blds + (wn * 64 + nt * 16 + fr) * 32 + fc);
#pragma unroll
    for (int mt = 0; mt < 4; ++mt)
#pragma unroll
      for (int nt = 0; nt < 4; ++nt)
        acc[mt][nt] = __builtin_amdgcn_mfma_f32_16x16x32_f16(af[mt], bf[nt], acc[mt][nt], 0, 0, 0);
    __syncthreads();
  }
#pragma unroll
  for (int nt = 0; nt < 4; ++nt) {
    int col = bcol + wn * 64 + nt * 16 + fr;
    int g = col / D_;
    int dcol = col - g * D_;
    int cg = dcol >> 4, c16 = dcol & 15;
    float bv = bih[col];
    f16* base = Cout + (((long)bm * 80 + cg) * 3 + g) * 2048 + c16;
#pragma unroll
    for (int mt = 0; mt < 4; ++mt) {
#pragma unroll
      for (int i = 0; i < 4; ++i) {
        int b = wm * 64 + mt * 16 + (l >> 4) * 4 + i;
        base[b * 16] = (f16)(acc[mt][nt][i] + bv);
      }
    }
  }
}

// ---------------- GRU scan: 640 blocks (8 rowgroups x 80 colgroups), W in registers ----------------
// rg = wg&7 (XCD-pure under round-robin dispatch; perf-only assumption).
// Each block: 16 h-rows x 16 D-cols x 3 gates. 4 waves = K-split (320 each).
// W fragments: 30 x f16x8 = 120 VGPRs per wave, loaded once, reused 256 steps -> zero LDS-W traffic.
// h stores: sc1 write-through (LLC); h loads: plain cached; staleness: NBUF rotation + fence/16 steps.
// Barrier per rowgroup: 40 shards x 2 arrivals; wave0 lanes 0..39 poll in parallel.
// __launch_bounds__(256,3): VGPR<=168 -> 3 blocks/CU capacity (768 >= 640, co-residency guaranteed).
__global__ __launch_bounds__(256, 3) void k_scan(const f16* __restrict__ whh16,
                                                 const f16* __restrict__ xproj,
                                                 const float* __restrict__ bhh,
                                                 f16* __restrict__ h16, float* __restrict__ h32,
                                                 unsigned* __restrict__ bar) {
  __shared__ float red[4][3][256];  // 12 KB k-partial exchange
  int wg = blockIdx.x;
  int rg = wg & 7, cg = wg >> 3;       // rg 0..7 (16 rows), cg 0..79 (16 D-cols)
  int r0 = rg * 16, d0 = cg * 16;
  int tid = threadIdx.x, w = tid >> 6, l = tid & 63;
  int fr = l & 15, fq = l >> 4;        // MFMA fragment coords
  int erow = tid >> 4, ecol = tid & 15;  // this thread's output element
  unsigned* mycnt = bar + (rg * 40 + (cg % 40)) * 32;  // 2 blocks per shard line

  // ---- load W fragments into persistent registers (once; reused 256 steps) ----
  // lane l holds W[g*D_ + d0 + fr][w*320 + j*32 + fq*8 .. +8]
  const f16* wbase = whh16 + (long)(d0 + fr) * D_ + w * 320 + fq * 8;
  f16x8 wf[10][3];
#pragma unroll
  for (int j = 0; j < 10; ++j)
#pragma unroll
    for (int g = 0; g < 3; ++g)
      wf[j][g] = *(const f16x8*)(wbase + (long)g * (D_ * D_) + j * 32);

  // zero own tile of h buffer 0 (sc1 write-through, paired u32)
  if ((tid & 1) == 0) {
    unsigned* p = (unsigned*)(h16 + (r0 + erow) * D_ + d0 + ecol);
    __hip_atomic_store(p, 0u, __ATOMIC_RELAXED, __HIP_MEMORY_SCOPE_AGENT);
  }

  float bh0 = bhh[0 * D_ + d0 + ecol];
  float bh1 = bhh[1 * D_ + d0 + ecol];
  float bh2 = bhh[2 * D_ + d0 + ecol];
  float hreg = 0.f;
  f16 xr, xz, xn;

  auto prefetch_x = [&](int tt) {
    const f16* xs = xproj + (((long)tt * 80 + cg) * 3) * 2048 + (r0 + erow) * 16 + ecol;
    xr = xs[0];
    xz = xs[2048];
    xn = xs[4096];
  };
  auto poll = [&](unsigned target) {
    unsigned it = 0;
    for (;;) {
      unsigned v = target;
      if (l < 40)
        v = __hip_atomic_load(bar + (rg * 40 + l) * 32, __ATOMIC_RELAXED, __HIP_MEMORY_SCOPE_AGENT);
      if (__all(v >= target)) break;
      __builtin_amdgcn_s_sleep(1);
      if (++it > 500000u) {  // paranoia: RMW reads the coherent point
        if (l < 40)
          v = __hip_atomic_fetch_add(bar + (rg * 40 + l) * 32, 0u, __ATOMIC_RELAXED,
                                     __HIP_MEMORY_SCOPE_AGENT);
        if (__all(v >= target)) break;
        it = 0;
      }
    }
  };

  prefetch_x(0);

  // initial barrier + cross-replay cache scrub
  __syncthreads();
  if (tid == 0)
    __hip_atomic_fetch_add(mycnt, 1u, __ATOMIC_RELAXED, __HIP_MEMORY_SCOPE_AGENT);
  if (tid < 64) {
    poll(2u);
    if (tid == 0) __builtin_amdgcn_fence(__ATOMIC_ACQUIRE, "agent");
  }
  __syncthreads();

  const f16* abase = (const f16*)h16 + (long)(r0 + fr) * D_ + w * 320 + fq * 8;
  unsigned tgt = 4u;
  for (int t = 0; t < T_; ++t) {
    const f16* arow = abase + (long)(t & (NBUF - 1)) * (B_ * D_);
    f32x4 acc0 = {}, acc1 = {}, acc2 = {};
#pragma unroll
    for (int j = 0; j < 10; ++j) {
      f16x8 a = *(const f16x8*)(arow + j * 32);  // plain cached (XCD-hot L2)
      acc0 = __builtin_amdgcn_mfma_f32_16x16x32_f16(a, wf[j][0], acc0, 0, 0, 0);
      acc1 = __builtin_amdgcn_mfma_f32_16x16x32_f16(a, wf[j][1], acc1, 0, 0, 0);
      acc2 = __builtin_amdgcn_mfma_f32_16x16x32_f16(a, wf[j][2], acc2, 0, 0, 0);
    }
    // k-reduce via LDS (XOR-swizzled: 2-way max on write, conflict-free read)
#pragma unroll
    for (int i = 0; i < 4; ++i) {
      int pos = (((fq * 4 + i) * 16) + fr) ^ (fq << 2);
      red[w][0][pos] = acc0[i];
      red[w][1][pos] = acc1[i];
      red[w][2][pos] = acc2[i];
    }
    __syncthreads();
    int pr = tid ^ ((tid >> 6) << 2);
    float s0 = red[0][0][pr] + red[1][0][pr] + red[2][0][pr] + red[3][0][pr];
    float s1 = red[0][1][pr] + red[1][1][pr] + red[2][1][pr] + red[3][1][pr];
    float s2 = red[0][2][pr] + red[1][2][pr] + red[2][2][pr] + red[3][2][pr];
    float r = 1.f / (1.f + __expf(-((float)xr + s0 + bh0)));
    float z = 1.f / (1.f + __expf(-((float)xz + s1 + bh1)));
    float pn = (float)xn + r * (s2 + bh2);
    pn = fminf(fmaxf(pn, -30.f), 30.f);
    float e2 = __expf(-2.f * pn);
    float nn = (1.f - e2) / (1.f + e2);
    float hv = (1.f - z) * nn + z * hreg;
    hreg = hv;
    if (t == T_ - 1) break;
    // store h_{t+1}: paired-u32 sc1 write-through
    unsigned short bits = __builtin_bit_cast(unsigned short, (f16)hv);
    unsigned other = (unsigned)__shfl_xor((int)bits, 1);
    if ((tid & 1) == 0) {
      unsigned val = (unsigned)bits | (other << 16);
      f16* hn = h16 + (long)((t + 1) & (NBUF - 1)) * (B_ * D_);
      __hip_atomic_store((unsigned*)(hn + (r0 + erow) * D_ + d0 + ecol), val, __ATOMIC_RELAXED,
                         __HIP_MEMORY_SCOPE_AGENT);
    }
    __syncthreads();  // drains sc1 stores (vmcnt) + closes red[] WAR window
    if (tid == 0)
      __hip_atomic_fetch_add(mycnt, 1u, __ATOMIC_RELAXED, __HIP_MEMORY_SCOPE_AGENT);
    prefetch_x(t + 1);  // in flight during the poll
    if (tid < 64) {
      poll(tgt);
      if (tid == 0 && (((t + 1) & (NBUF - 1)) == 0))
        __builtin_amdgcn_fence(__ATOMIC_ACQUIRE, "agent");  // periodic stale-line scrub
    }
    __syncthreads();
    tgt += 2u;
  }
  // final h in fp32 for the scores kernel
  h32[(r0 + erow) * D_ + d0 + ecol] = hreg;
}

// ---------------- scores: out[b][c] = sum_d h[b][d]*cand[b][c][d] (fp32) ----------------
__global__ __launch_bounds__(256) void k_scores(const float* __restrict__ h32,
                                                const float* __restrict__ cand,
                                                float* __restrict__ out) {
  int gw = blockIdx.x * 4 + (threadIdx.x >> 6);
  int l = threadIdx.x & 63;
  int b = gw / C_, c = gw % C_;
  const float* hp = h32 + (long)b * D_;
  const float* cp = cand + ((long)b * C_ + c) * D_;
  float s = 0.f;
#pragma unroll
  for (int q = 0; q < 5; ++q) {
    int d = q * 256 + l * 4;
    float4 hv = *(const float4*)(hp + d);
    float4 cv = *(const float4*)(cp + d);
    s += hv.x * cv.x + hv.y * cv.y + hv.z * cv.z + hv.w * cv.w;
  }
#pragma unroll
  for (int off = 32; off > 0; off >>= 1) s += __shfl_down(s, off);
  if (l == 0) out[(long)b * C_ + c] = s;
}

extern "C" void kernel_launch(void* const* d_in, const int* in_sizes, int n_in, void* d_out,
                              int out_size, void* d_ws, size_t ws_size, hipStream_t stream) {
  const float* seq = (const float*)d_in[0];
  const float* cand = (const float*)d_in[1];
  const float* wih = (const float*)d_in[2];
  const float* whh = (const float*)d_in[3];
  const float* bih = (const float*)d_in[4];
  const float* bhh = (const float*)d_in[5];
  char* ws = (char*)d_ws;
  f16* seqb = (f16*)(ws + O_SEQB);
  f16* wih16 = (f16*)(ws + O_WIH);
  f16* whh16 = (f16*)(ws + O_WHH);
  f16* xp = (f16*)(ws + O_XP);
  f16* h16 = (f16*)(ws + O_H16);  // rotating buffers, overlapping seqb (dead by then)
  float* h32 = (float*)(ws + O_H32);
  unsigned* bar = (unsigned*)(ws + O_BAR);

  k_convert<<<2048, 256, 0, stream>>>(seq, wih, whh, seqb, wih16, whh16, bar);
  k_xproj<<<7680, 256, 0, stream>>>(seqb, wih16, bih, xp);
  k_scan<<<640, 256, 0, stream>>>(whh16, xp, bhh, h16, h32, bar);
  k_scores<<<3200, 256, 0, stream>>>(h32, cand, (float*)d_out);
}

// Round 9
// 2261.584 us; speedup vs baseline: 3.3615x; 1.0593x over previous
//
#include <hip/hip_runtime.h>
#include <hip/hip_bf16.h>

typedef _Float16 f16;
typedef _Float16 f16x8 __attribute__((ext_vector_type(8)));
typedef float f32x4 __attribute__((ext_vector_type(4)));

#define B_ 128
#define T_ 256
#define D_ 1280
#define G3_ 3840
#define C_ 100
#define TB_ 32768  /* T_*B_ */
#define NBUF 16    /* rotating h buffers */

// ---- workspace layout (bytes) ----
#define O_H16  0ull                 // f16 [NBUF][B_][D_]  (5.25 MB, inside dead seqb region)
#define O_SEQB 0ull                 // f16 [TB_][D_]
#define O_WIH  83886080ull          // f16 [G3_][D_]
#define O_WHH  93716480ull          // f16 [G3_][D_]
#define O_XP   103546880ull         // f16 [T_][80][3][128][16] compact slabs
#define O_H32  355860480ull         // f32 [B_][D_]
#define O_BAR  356515840ull         // u32 counters: (rg*40+shard)*32 stride (128B)

// ---------------- conversion / init ----------------
__global__ void k_convert(const float* __restrict__ seq, const float* __restrict__ wih,
                          const float* __restrict__ whh, f16* __restrict__ seqb,
                          f16* __restrict__ wih16, f16* __restrict__ whh16,
                          unsigned* __restrict__ bar) {
  if (blockIdx.x == 0) {
    for (int j = threadIdx.x; j < 10240; j += 256)
      __hip_atomic_store(bar + j, 0u, __ATOMIC_RELAXED, __HIP_MEMORY_SCOPE_AGENT);
  }
  const long NSEQ = (long)TB_ * (D_ / 8);
  const long NW = (long)G3_ * (D_ / 8);
  const long total = NSEQ + 2 * NW;
  for (long i = (long)blockIdx.x * blockDim.x + threadIdx.x; i < total;
       i += (long)gridDim.x * blockDim.x) {
    const float* src;
    f16* dst;
    if (i < NSEQ) {
      long row = i / (D_ / 8), c = i % (D_ / 8);
      long t = row >> 7, b = row & 127;
      src = seq + ((b * T_ + t) * (long)D_ + c * 8);
      dst = seqb + (row * (long)D_ + c * 8);
    } else if (i < NSEQ + NW) {
      long j = i - NSEQ;
      src = wih + j * 8;
      dst = wih16 + j * 8;
    } else {
      long j = i - NSEQ - NW;
      src = whh + j * 8;
      dst = whh16 + j * 8;
    }
    float4 a = *(const float4*)src, b4 = *(const float4*)(src + 4);
    f16x8 o;
    o[0] = (f16)a.x; o[1] = (f16)a.y; o[2] = (f16)a.z; o[3] = (f16)a.w;
    o[4] = (f16)b4.x; o[5] = (f16)b4.y; o[6] = (f16)b4.z; o[7] = (f16)b4.w;
    *(f16x8*)dst = o;
  }
}

// ---------------- x_proj GEMM -> compact slab layout [t][cg][g][b][c16] ----------------
__device__ __forceinline__ void gl_lds16(const f16* g, f16* lds) {
  __builtin_amdgcn_global_load_lds((const __attribute__((address_space(1))) void*)g,
                                   (__attribute__((address_space(3))) void*)lds, 16, 0, 0);
}

__global__ __launch_bounds__(256) void k_xproj(const f16* __restrict__ A, const f16* __restrict__ Bw,
                                               const float* __restrict__ bih, f16* __restrict__ Cout) {
  __shared__ f16 Alds[128 * 32];
  __shared__ f16 Blds[128 * 32];
  int bid = blockIdx.x;
  int sb = bid / 240;
  int wi = bid % 240;
  int bm = sb * 8 + (wi & 7);
  int bn = wi >> 3;
  long brow = (long)bm * 128;
  int bcol = bn * 128;
  int tid = threadIdx.x, w = tid >> 6, l = tid & 63;
  int wm = w & 1, wn = w >> 1;

  f32x4 acc[4][4] = {};

  int sr = w * 32 + (l >> 2);
  int sc = (l & 3) * 8;
  const f16* gA = A + (brow + sr) * (long)D_ + sc;
  const f16* gB = Bw + (long)(bcol + sr) * D_ + sc;
  f16* lAw = Alds + (w * 32) * 32;
  f16* lBw = Blds + (w * 32) * 32;

  int fr = l & 15, fc = (l >> 4) * 8;

  for (int kb = 0; kb < 40; ++kb) {
    const f16* a0 = gA + kb * 32;
    const f16* b0 = gB + kb * 32;
    gl_lds16(a0, lAw);
    gl_lds16(a0 + 16 * D_, lAw + 16 * 32);
    gl_lds16(b0, lBw);
    gl_lds16(b0 + 16 * D_, lBw + 16 * 32);
    __syncthreads();
    f16x8 af[4], bf[4];
#pragma unroll
    for (int mt = 0; mt < 4; ++mt) af[mt] = *(const f16x8*)(Alds + (wm * 64 + mt * 16 + fr) * 32 + fc);
#pragma unroll
    for (int nt = 0; nt < 4; ++nt) bf[nt] = *(const f16x8*)(Blds + (wn * 64 + nt * 16 + fr) * 32 + fc);
#pragma unroll
    for (int mt = 0; mt < 4; ++mt)
#pragma unroll
      for (int nt = 0; nt < 4; ++nt)
        acc[mt][nt] = __builtin_amdgcn_mfma_f32_16x16x32_f16(af[mt], bf[nt], acc[mt][nt], 0, 0, 0);
    __syncthreads();
  }
#pragma unroll
  for (int nt = 0; nt < 4; ++nt) {
    int col = bcol + wn * 64 + nt * 16 + fr;
    int g = col / D_;
    int dcol = col - g * D_;
    int cg = dcol >> 4, c16 = dcol & 15;
    float bv = bih[col];
    f16* base = Cout + (((long)bm * 80 + cg) * 3 + g) * 2048 + c16;
#pragma unroll
    for (int mt = 0; mt < 4; ++mt) {
#pragma unroll
      for (int i = 0; i < 4; ++i) {
        int b = wm * 64 + mt * 16 + (l >> 4) * 4 + i;
        base[b * 16] = (f16)(acc[mt][nt][i] + bv);
      }
    }
  }
}

// ---------------- GRU scan: 320 blocks (4 rowgroups x 32 rows, 80 colgroups), W pinned in regs ----------------
// Each block: 32 h-rows x 16 D-cols x 3 gates; 4 waves K-split (320 each).
// W fragments: 30 x f16x8 = 120 VGPRs, loaded once, PINNED via empty asm (anti-rematerialization).
// launch_bounds(256,2): VGPR cap ~256 (no-spill headroom); 2 blocks/CU capacity = 512 >= 320.
// h stores: sc1 write-through (LLC); h loads: plain cached; staleness: NBUF rotation + fence/16 steps.
// Barrier per rowgroup: 40 shards x 2 arrivals; wave0 lanes 0..39 poll in parallel.
__global__ __launch_bounds__(256, 2) void k_scan(const f16* __restrict__ whh16,
                                                 const f16* __restrict__ xproj,
                                                 const float* __restrict__ bhh,
                                                 f16* __restrict__ h16, float* __restrict__ h32,
                                                 unsigned* __restrict__ bar) {
  __shared__ float red[4][3][2][256];  // 24 KB k-partial exchange
  int wg = blockIdx.x;
  int rg = wg & 3, cg = wg >> 2;       // 4 rowgroups (32 rows), 80 colgroups (16 cols)
  int r0 = rg * 32, d0 = cg * 16;
  int tid = threadIdx.x, w = tid >> 6, l = tid & 63;
  int fr = l & 15, fq = l >> 4;        // MFMA fragment coords
  int er = tid >> 4, ec = tid & 15;    // output element coords (rows er, er+16)
  unsigned* mycnt = bar + (rg * 40 + (cg % 40)) * 32;  // 2 blocks per shard line

  // ---- load W fragments into persistent registers (once; reused 256 steps) ----
  const f16* wbase = whh16 + (long)(d0 + fr) * D_ + w * 320 + fq * 8;
  f16x8 wf[10][3];
#pragma unroll
  for (int j = 0; j < 10; ++j)
#pragma unroll
    for (int g = 0; g < 3; ++g)
      wf[j][g] = *(const f16x8*)(wbase + (long)g * (D_ * D_) + j * 32);
  // PIN: asm output cannot be rematerialized -> W stays register-resident
#pragma unroll
  for (int j = 0; j < 10; ++j)
#pragma unroll
    for (int g = 0; g < 3; ++g)
      asm volatile("" : "+v"(wf[j][g]));

  // zero own tile of h buffer 0 (sc1 write-through, paired u32)
  if ((tid & 1) == 0) {
#pragma unroll
    for (int m = 0; m < 2; ++m) {
      unsigned* p = (unsigned*)(h16 + (r0 + m * 16 + er) * D_ + d0 + ec);
      __hip_atomic_store(p, 0u, __ATOMIC_RELAXED, __HIP_MEMORY_SCOPE_AGENT);
    }
  }

  float bh0 = bhh[0 * D_ + d0 + ec];
  float bh1 = bhh[1 * D_ + d0 + ec];
  float bh2 = bhh[2 * D_ + d0 + ec];
  float hreg[2] = {0.f, 0.f};
  f16 xg[2][3];

  auto prefetch_x = [&](int tt) {
    const f16* xs = xproj + (((long)tt * 80 + cg) * 3) * 2048;
#pragma unroll
    for (int m = 0; m < 2; ++m) {
      int off = (r0 + m * 16) * 16 + tid;
      xg[m][0] = xs[off];
      xg[m][1] = xs[2048 + off];
      xg[m][2] = xs[4096 + off];
    }
  };
  auto poll = [&](unsigned target) {
    unsigned it = 0;
    for (;;) {
      unsigned v = target;
      if (l < 40)
        v = __hip_atomic_load(bar + (rg * 40 + l) * 32, __ATOMIC_RELAXED, __HIP_MEMORY_SCOPE_AGENT);
      if (__all(v >= target)) break;
      __builtin_amdgcn_s_sleep(1);
      if (++it > 500000u) {  // paranoia: RMW reads the coherent point
        if (l < 40)
          v = __hip_atomic_fetch_add(bar + (rg * 40 + l) * 32, 0u, __ATOMIC_RELAXED,
                                     __HIP_MEMORY_SCOPE_AGENT);
        if (__all(v >= target)) break;
        it = 0;
      }
    }
  };

  prefetch_x(0);

  // initial barrier + cross-replay cache scrub
  __syncthreads();
  if (tid == 0)
    __hip_atomic_fetch_add(mycnt, 1u, __ATOMIC_RELAXED, __HIP_MEMORY_SCOPE_AGENT);
  if (tid < 64) {
    poll(2u);
    if (tid == 0) __builtin_amdgcn_fence(__ATOMIC_ACQUIRE, "agent");
  }
  __syncthreads();

  unsigned tgt = 4u;
  for (int t = 0; t < T_; ++t) {
    const f16* hc = h16 + (long)(t & (NBUF - 1)) * (B_ * D_);
    const f16* ar0 = hc + (long)(r0 + fr) * D_ + w * 320 + fq * 8;
    f32x4 acc[2][3] = {};
#pragma unroll
    for (int j = 0; j < 10; ++j) {
      f16x8 a0 = *(const f16x8*)(ar0 + j * 32);           // rows r0..r0+15
      f16x8 a1 = *(const f16x8*)(ar0 + 16 * D_ + j * 32); // rows r0+16..r0+31
      acc[0][0] = __builtin_amdgcn_mfma_f32_16x16x32_f16(a0, wf[j][0], acc[0][0], 0, 0, 0);
      acc[0][1] = __builtin_amdgcn_mfma_f32_16x16x32_f16(a0, wf[j][1], acc[0][1], 0, 0, 0);
      acc[0][2] = __builtin_amdgcn_mfma_f32_16x16x32_f16(a0, wf[j][2], acc[0][2], 0, 0, 0);
      acc[1][0] = __builtin_amdgcn_mfma_f32_16x16x32_f16(a1, wf[j][0], acc[1][0], 0, 0, 0);
      acc[1][1] = __builtin_amdgcn_mfma_f32_16x16x32_f16(a1, wf[j][1], acc[1][1], 0, 0, 0);
      acc[1][2] = __builtin_amdgcn_mfma_f32_16x16x32_f16(a1, wf[j][2], acc[1][2], 0, 0, 0);
    }
    // k-reduce via LDS
#pragma unroll
    for (int m = 0; m < 2; ++m)
#pragma unroll
      for (int g = 0; g < 3; ++g)
#pragma unroll
        for (int i = 0; i < 4; ++i)
          red[w][g][m][(((fq * 4 + i) * 16) + fr) ^ (fq << 2)] = acc[m][g][i];
    __syncthreads();
    int pr = tid ^ ((tid >> 6) << 2);
    float hnew[2];
#pragma unroll
    for (int m = 0; m < 2; ++m) {
      float s0 = red[0][0][m][pr] + red[1][0][m][pr] + red[2][0][m][pr] + red[3][0][m][pr];
      float s1 = red[0][1][m][pr] + red[1][1][m][pr] + red[2][1][m][pr] + red[3][1][m][pr];
      float s2 = red[0][2][m][pr] + red[1][2][m][pr] + red[2][2][m][pr] + red[3][2][m][pr];
      float r = 1.f / (1.f + __expf(-((float)xg[m][0] + s0 + bh0)));
      float z = 1.f / (1.f + __expf(-((float)xg[m][1] + s1 + bh1)));
      float pn = (float)xg[m][2] + r * (s2 + bh2);
      pn = fminf(fmaxf(pn, -30.f), 30.f);
      float e2 = __expf(-2.f * pn);
      float nn = (1.f - e2) / (1.f + e2);
      hnew[m] = (1.f - z) * nn + z * hreg[m];
      hreg[m] = hnew[m];
    }
    if (t == T_ - 1) break;
    // store h_{t+1}: paired-u32 sc1 write-through
    f16* hn = h16 + (long)((t + 1) & (NBUF - 1)) * (B_ * D_);
#pragma unroll
    for (int m = 0; m < 2; ++m) {
      unsigned short bits = __builtin_bit_cast(unsigned short, (f16)hnew[m]);
      unsigned other = (unsigned)__shfl_xor((int)bits, 1);
      if ((tid & 1) == 0) {
        unsigned val = (unsigned)bits | (other << 16);
        __hip_atomic_store((unsigned*)(hn + (r0 + m * 16 + er) * D_ + d0 + ec), val,
                           __ATOMIC_RELAXED, __HIP_MEMORY_SCOPE_AGENT);
      }
    }
    __syncthreads();  // drains sc1 stores (vmcnt) + closes red[] WAR window
    if (tid == 0)
      __hip_atomic_fetch_add(mycnt, 1u, __ATOMIC_RELAXED, __HIP_MEMORY_SCOPE_AGENT);
    prefetch_x(t + 1);  // in flight during the poll
    if (tid < 64) {
      poll(tgt);
      if (tid == 0 && (((t + 1) & (NBUF - 1)) == 0))
        __builtin_amdgcn_fence(__ATOMIC_ACQUIRE, "agent");  // periodic stale-line scrub
    }
    __syncthreads();
    tgt += 2u;
  }
  // final h in fp32 for the scores kernel
#pragma unroll
  for (int m = 0; m < 2; ++m) h32[(r0 + m * 16 + er) * D_ + d0 + ec] = hreg[m];
}

// ---------------- scores: out[b][c] = sum_d h[b][d]*cand[b][c][d] (fp32) ----------------
__global__ __launch_bounds__(256) void k_scores(const float* __restrict__ h32,
                                                const float* __restrict__ cand,
                                                float* __restrict__ out) {
  int gw = blockIdx.x * 4 + (threadIdx.x >> 6);
  int l = threadIdx.x & 63;
  int b = gw / C_, c = gw % C_;
  const float* hp = h32 + (long)b * D_;
  const float* cp = cand + ((long)b * C_ + c) * D_;
  float s = 0.f;
#pragma unroll
  for (int q = 0; q < 5; ++q) {
    int d = q * 256 + l * 4;
    float4 hv = *(const float4*)(hp + d);
    float4 cv = *(const float4*)(cp + d);
    s += hv.x * cv.x + hv.y * cv.y + hv.z * cv.z + hv.w * cv.w;
  }
#pragma unroll
  for (int off = 32; off > 0; off >>= 1) s += __shfl_down(s, off);
  if (l == 0) out[(long)b * C_ + c] = s;
}

extern "C" void kernel_launch(void* const* d_in, const int* in_sizes, int n_in, void* d_out,
                              int out_size, void* d_ws, size_t ws_size, hipStream_t stream) {
  const float* seq = (const float*)d_in[0];
  const float* cand = (const float*)d_in[1];
  const float* wih = (const float*)d_in[2];
  const float* whh = (const float*)d_in[3];
  const float* bih = (const float*)d_in[4];
  const float* bhh = (const float*)d_in[5];
  char* ws = (char*)d_ws;
  f16* seqb = (f16*)(ws + O_SEQB);
  f16* wih16 = (f16*)(ws + O_WIH);
  f16* whh16 = (f16*)(ws + O_WHH);
  f16* xp = (f16*)(ws + O_XP);
  f16* h16 = (f16*)(ws + O_H16);  // rotating buffers, overlapping seqb (dead by then)
  float* h32 = (float*)(ws + O_H32);
  unsigned* bar = (unsigned*)(ws + O_BAR);

  k_convert<<<2048, 256, 0, stream>>>(seq, wih, whh, seqb, wih16, whh16, bar);
  k_xproj<<<7680, 256, 0, stream>>>(seqb, wih16, bih, xp);
  k_scan<<<320, 256, 0, stream>>>(whh16, xp, bhh, h16, h32, bar);
  k_scores<<<3200, 256, 0, stream>>>(h32, cand, (float*)d_out);
}